// Round 8
// baseline (188.372 us; speedup 1.0000x reference)
//
#include <hip/hip_runtime.h>
#include <hip/hip_bf16.h>

#define BB 2
#define SS 4096
#define CC 512
#define HH 8
#define DD 64
#define MM (BB*SS)

typedef __bf16 bf16;
typedef __attribute__((ext_vector_type(8))) __bf16 bf16x8;
typedef __attribute__((ext_vector_type(4))) __bf16 bf16x4;
typedef __attribute__((ext_vector_type(4))) float f32x4;

#define LP 72  // attn LDS row stride (64 + 8 pad) — attn kernel only
#define QSCALE 0.18033688f  // 1/sqrt(64) * log2(e), folded into Wq at cvt time

__device__ __forceinline__ bf16x8 cvt8(const float4 a, const float4 b) {
  bf16x8 r;
  r[0]=(bf16)a.x; r[1]=(bf16)a.y; r[2]=(bf16)a.z; r[3]=(bf16)a.w;
  r[4]=(bf16)b.x; r[5]=(bf16)b.y; r[6]=(bf16)b.z; r[7]=(bf16)b.w;
  return r;
}

// async global(16B/lane) -> LDS(base + lane*16), m97 pattern
__device__ __forceinline__ void gl16(const bf16* g, bf16* l) {
  __builtin_amdgcn_global_load_lds(
      (const __attribute__((address_space(1))) void*)g,
      (__attribute__((address_space(3))) void*)l, 16, 0, 0);
}

// ---------------------------------------------------------------------------
// Kernel 0: elementwise fp32 -> bf16 (X).
// ---------------------------------------------------------------------------
__global__ __launch_bounds__(256) void cvt_f32_bf16(
    const float* __restrict__ src, bf16* __restrict__ dst)
{
  size_t e = ((size_t)blockIdx.x * 256 + threadIdx.x) * 8;
  float4 a = ((const float4*)(src + e))[0];
  float4 b = ((const float4*)(src + e))[1];
  *(bf16x8*)(dst + e) = cvt8(a, b);
}

// ---------------------------------------------------------------------------
// Kernel 0b: fused Wq|Wk|Wv -> Wb [1536][512] (QSCALE on Wq) AND Wo -> Wob.
// Wob no longer aliases qp, so this runs up-front (one launch saved).
// ---------------------------------------------------------------------------
__global__ __launch_bounds__(256) void cvt_w(
    const float* __restrict__ Wq, const float* __restrict__ Wk,
    const float* __restrict__ Wv, const float* __restrict__ Wo,
    bf16* __restrict__ Wb, bf16* __restrict__ Wob)
{
  size_t e = ((size_t)blockIdx.x * 256 + threadIdx.x) * 8;  // < 1048576
  if (e < 786432) {
    const int tens = (int)(e >> 18);                        // 262144 per W
    const float* src = ((tens == 0) ? Wq : (tens == 1) ? Wk : Wv) + (e & 262143);
    const float sc = (tens == 0) ? QSCALE : 1.f;
    float4 a = ((const float4*)src)[0];
    float4 b = ((const float4*)src)[1];
    bf16x8 r;
    r[0]=(bf16)(a.x*sc); r[1]=(bf16)(a.y*sc); r[2]=(bf16)(a.z*sc); r[3]=(bf16)(a.w*sc);
    r[4]=(bf16)(b.x*sc); r[5]=(bf16)(b.y*sc); r[6]=(bf16)(b.z*sc); r[7]=(bf16)(b.w*sc);
    *(bf16x8*)(Wb + e) = r;
  } else {
    const size_t eo = e - 786432;                           // < 262144
    float4 a = ((const float4*)(Wo + eo))[0];
    float4 b = ((const float4*)(Wo + eo))[1];
    *(bf16x8*)(Wob + eo) = cvt8(a, b);
  }
}

// ---------------------------------------------------------------------------
// Kernel 1: fused QKV projection — R7: staging via global_load_lds(16B) into
// LINEAR [64][64] LDS tiles (m97 ladder step: lane-linear dest required, so
// the LP=72 pad is dropped; m93->m97 measured +69%). MFMA mosaic, epilogue,
// and output layouts unchanged (stride 72 -> 64 only).
// ---------------------------------------------------------------------------
__global__ __launch_bounds__(256) void qkv_gemm(
    const bf16* __restrict__ Xb, const bf16* __restrict__ Wb,
    bf16* __restrict__ qp, bf16* __restrict__ kp, bf16* __restrict__ vtp)
{
  __shared__ bf16 Aa[64*64];
  __shared__ bf16 Ab[64*64];
  __shared__ bf16 Ba[64*64];
  __shared__ bf16 Bb[64*64];
  const int m0  = blockIdx.x * 128;        // m-pair: m0, m0+64
  const int nf0 = blockIdx.y * 128;        // n-pair within fused [0,1536)
  const int tens = nf0 >> 9;               // 128 divides 512 -> uniform
  const int n0 = nf0 & 511;                // first n-strip; second is n0+64

  const int t = threadIdx.x;
  const int w = t >> 6;
  const int lane = t & 63;
  const int l15 = lane & 15;
  const int quad = lane >> 4;
  // per-lane source position for global_load_lds staging:
  // wave w covers rows w*16 .. w*16+15 of each 64x64 tile, 2 instrs x 8 rows
  const int sr = lane >> 3;                // 0..7 row within 8-row slab
  const int sc = (lane & 7) * 8;           // 0..56 col (8 elems = 16B)

  f32x4 acc[2][2][4];  // [mi][ni][nt]
  #pragma unroll
  for (int mi = 0; mi < 2; ++mi)
    #pragma unroll
    for (int ni = 0; ni < 2; ++ni)
      #pragma unroll
      for (int nt = 0; nt < 4; ++nt)
        #pragma unroll
        for (int r = 0; r < 4; ++r) acc[mi][ni][nt][r] = 0.f;

  for (int k0 = 0; k0 < CC; k0 += 64) {
    __syncthreads();
    {
      const bf16* pa = Xb + (size_t)(m0 + w*16 + sr) * CC + k0 + sc;
      gl16(pa,             &Aa[w*1024]);
      gl16(pa + 8*CC,      &Aa[w*1024 + 512]);
      const bf16* pb = Xb + (size_t)(m0 + 64 + w*16 + sr) * CC + k0 + sc;
      gl16(pb,             &Ab[w*1024]);
      gl16(pb + 8*CC,      &Ab[w*1024 + 512]);
      const bf16* p1 = Wb + (size_t)(nf0 + w*16 + sr) * CC + k0 + sc;
      gl16(p1,             &Ba[w*1024]);
      gl16(p1 + 8*CC,      &Ba[w*1024 + 512]);
      const bf16* p2 = Wb + (size_t)(nf0 + 64 + w*16 + sr) * CC + k0 + sc;
      gl16(p2,             &Bb[w*1024]);
      gl16(p2 + 8*CC,      &Bb[w*1024 + 512]);
    }
    __syncthreads();
    #pragma unroll
    for (int c = 0; c < 2; ++c) {
      bf16x8 afa = *(const bf16x8*)&Aa[(w*16 + l15)*64 + c*32 + quad*8];
      bf16x8 afb = *(const bf16x8*)&Ab[(w*16 + l15)*64 + c*32 + quad*8];
      #pragma unroll
      for (int nt = 0; nt < 4; ++nt) {
        bf16x8 ba = *(const bf16x8*)&Ba[(nt*16 + l15)*64 + c*32 + quad*8];
        bf16x8 bb = *(const bf16x8*)&Bb[(nt*16 + l15)*64 + c*32 + quad*8];
        acc[0][0][nt] = __builtin_amdgcn_mfma_f32_16x16x32_bf16(afa, ba, acc[0][0][nt], 0, 0, 0);
        acc[1][0][nt] = __builtin_amdgcn_mfma_f32_16x16x32_bf16(afb, ba, acc[1][0][nt], 0, 0, 0);
        acc[0][1][nt] = __builtin_amdgcn_mfma_f32_16x16x32_bf16(afa, bb, acc[0][1][nt], 0, 0, 0);
        acc[1][1][nt] = __builtin_amdgcn_mfma_f32_16x16x32_bf16(afb, bb, acc[1][1][nt], 0, 0, 0);
      }
    }
  }

  bf16* plane = (tens == 0) ? qp : ((tens == 1) ? kp : vtp);
  const int c8 = (t & 7) * 8;

  auto epi = [&](const f32x4* as, int mt0, int nb) {
    const int b = mt0 >> 12, s0g = mt0 & 4095;
    const int h = nb >> 6;
    __syncthreads();
    if (tens < 2) {
      #pragma unroll
      for (int nt = 0; nt < 4; ++nt)
        #pragma unroll
        for (int r = 0; r < 4; ++r)
          Aa[(w*16 + quad*4 + r)*64 + nt*16 + l15] = (bf16)as[nt][r];
    } else {
      #pragma unroll
      for (int nt = 0; nt < 4; ++nt)
        #pragma unroll
        for (int r = 0; r < 4; ++r)
          Aa[(nt*16 + l15)*64 + w*16 + quad*4 + r] = (bf16)as[nt][r];
    }
    __syncthreads();
    #pragma unroll
    for (int i = 0; i < 2; ++i) {
      const int row = (t >> 3) + 32*i;
      bf16x8 v = *(const bf16x8*)&Aa[row*64 + c8];
      if (tens < 2) {
        *(bf16x8*)&plane[((size_t)((b*HH + h)*SS) + s0g + row)*DD + c8] = v;
      } else {
        *(bf16x8*)&plane[((size_t)((b*HH + h)*DD) + row)*SS + s0g + c8] = v;
      }
    }
  };

  epi(acc[0][0], m0,      n0);
  epi(acc[1][0], m0 + 64, n0);
  epi(acc[0][1], m0,      n0 + 64);
  epi(acc[1][1], m0 + 64, n0 + 64);
}

// ---------------------------------------------------------------------------
// Kernel 2: flash attention — VERBATIM R6 green (split-K, ones-MFMA rowsum,
// kbh-split interleave, setprio). Frozen: LDS-port + barrier-burst bound;
// Nq=64 spills (o+qf=96 regs persistent vs 128 cap), 8-wave/SIMD needs <=64.
// ---------------------------------------------------------------------------
__global__ __launch_bounds__(512, 4) void attn_fa(
    const bf16* __restrict__ qpl, const bf16* __restrict__ kpl,
    const bf16* __restrict__ vtpl, bf16* __restrict__ aout)
{
  __shared__ __align__(16) bf16 smem[2 * 4 * 64 * LP];   // 73728 B

  const int t = threadIdx.x;
  const int w = t >> 6;                  // 0..7
  const int g = w >> 2;                  // k-group
  const int wl = w & 3;                  // wave within group -> q-strip
  const int lane = t & 63;
  const int l15 = lane & 15;
  const int quad = lane >> 4;

  const int lin = blockIdx.x;            // 0..511
  const int bh = lin & 15;               // fastest -> same XCD class per bh
  const int q0 = (lin >> 4) * 128;
  const size_t plane = (size_t)SS * DD;
  const bf16* Qp = qpl + (size_t)bh * plane;
  const bf16* Kp = kpl + (size_t)bh * plane;
  const bf16* Vg = vtpl + (size_t)bh * plane;

  bf16* Ktg = smem + g * (4*64*LP);      // K tiles buf0, buf1
  bf16* Vtg = Ktg + 2*64*LP;             // V tiles buf0, buf1

  bf16x8 qf[2][2];
  #pragma unroll
  for (int wq = 0; wq < 2; ++wq) {
    const bf16* qr = Qp + (size_t)(q0 + wl*32 + wq*16 + l15) * DD + quad*8;
    qf[wq][0] = *(const bf16x8*)qr;
    qf[wq][1] = *(const bf16x8*)(qr + 32);
  }

  f32x4 o[2][4];
  f32x4 osum[2];
  #pragma unroll
  for (int wq = 0; wq < 2; ++wq) {
    #pragma unroll
    for (int nt = 0; nt < 4; ++nt)
      #pragma unroll
      for (int r = 0; r < 4; ++r) o[wq][nt][r] = 0.f;
    #pragma unroll
    for (int r = 0; r < 4; ++r) osum[wq][r] = 0.f;
  }

  bf16x8 ones;
  #pragma unroll
  for (int i = 0; i < 8; ++i) ones[i] = (bf16)1.0f;

  const int t8  = t & 255;
  const int r0s = t8 >> 2;               // 0..63
  const int cs  = (t8 & 3) << 4;         // {0,16,32,48}
  const int K0  = ((t8 & 1) << 3) + (((t8 >> 1) & 1) << 5);  // {0,8,32,40}
  const int kbase = g << 11;             // g*2048

  bf16x8 ka0, ka1, va, vb;
  {
    ka0 = *(const bf16x8*)&Kp[(size_t)(kbase + r0s)*DD + cs];
    ka1 = *(const bf16x8*)&Kp[(size_t)(kbase + r0s)*DD + cs + 8];
    va  = *(const bf16x8*)&Vg[(size_t)r0s*SS + kbase + K0];
    vb  = *(const bf16x8*)&Vg[(size_t)r0s*SS + kbase + K0 + 16];
    *(bf16x8*)&Ktg[r0s*LP + cs]     = ka0;
    *(bf16x8*)&Ktg[r0s*LP + cs + 8] = ka1;
    bf16x8 vv;
    vv[0]=va[0]; vv[1]=va[1]; vv[2]=va[2]; vv[3]=va[3];
    vv[4]=vb[0]; vv[5]=vb[1]; vv[6]=vb[2]; vv[7]=vb[3];
    *(bf16x8*)&Vtg[r0s*LP + cs] = vv;
    vv[0]=va[4]; vv[1]=va[5]; vv[2]=va[6]; vv[3]=va[7];
    vv[4]=vb[4]; vv[5]=vb[5]; vv[6]=vb[6]; vv[7]=vb[7];
    *(bf16x8*)&Vtg[r0s*LP + cs + 8] = vv;
  }
  __syncthreads();

  for (int it = 0; it < 32; ++it) {
    const int cur = it & 1;
    if (it < 31) {
      const int kn = kbase + (it + 1) * 64;
      ka0 = *(const bf16x8*)&Kp[(size_t)(kn + r0s)*DD + cs];
      ka1 = *(const bf16x8*)&Kp[(size_t)(kn + r0s)*DD + cs + 8];
      va  = *(const bf16x8*)&Vg[(size_t)r0s*SS + kn + K0];
      vb  = *(const bf16x8*)&Vg[(size_t)r0s*SS + kn + K0 + 16];
    }

    const bf16* Ktc = Ktg + cur*(64*LP);
    const bf16* Vtc = Vtg + cur*(64*LP);

    f32x4 st[2][4];
    __builtin_amdgcn_s_setprio(1);
    #pragma unroll
    for (int nt = 0; nt < 4; ++nt) {
      bf16x8 kf0 = *(const bf16x8*)&Ktc[(nt*16 + l15)*LP + quad*8];
      bf16x8 kf1 = *(const bf16x8*)&Ktc[(nt*16 + l15)*LP + 32 + quad*8];
      #pragma unroll
      for (int wq = 0; wq < 2; ++wq) {
        f32x4 z; z[0]=z[1]=z[2]=z[3]=0.f;
        z = __builtin_amdgcn_mfma_f32_16x16x32_bf16(kf0, qf[wq][0], z, 0, 0, 0);
        z = __builtin_amdgcn_mfma_f32_16x16x32_bf16(kf1, qf[wq][1], z, 0, 0, 0);
        st[wq][nt] = z;
      }
    }
    __builtin_amdgcn_s_setprio(0);

    // ---- kbh = 0: exp/pack nt 0..1, then PV ----
    bf16x8 pb0[2];
    #pragma unroll
    for (int wq = 0; wq < 2; ++wq)
      #pragma unroll
      for (int nt = 0; nt < 2; ++nt)
        #pragma unroll
        for (int r = 0; r < 4; ++r)
          pb0[wq][(nt & 1)*4 + r] = (bf16)__builtin_amdgcn_exp2f(st[wq][nt][r]);

    __builtin_amdgcn_s_setprio(1);
    #pragma unroll
    for (int nt = 0; nt < 4; ++nt) {
      bf16x8 vf = *(const bf16x8*)&Vtc[(nt*16 + l15)*LP + quad*8];
      #pragma unroll
      for (int wq = 0; wq < 2; ++wq)
        o[wq][nt] = __builtin_amdgcn_mfma_f32_16x16x32_bf16(vf, pb0[wq], o[wq][nt], 0, 0, 0);
    }
    #pragma unroll
    for (int wq = 0; wq < 2; ++wq)
      osum[wq] = __builtin_amdgcn_mfma_f32_16x16x32_bf16(ones, pb0[wq], osum[wq], 0, 0, 0);
    __builtin_amdgcn_s_setprio(0);

    // ---- kbh = 1: exp/pack nt 2..3, then PV ----
    bf16x8 pb1[2];
    #pragma unroll
    for (int wq = 0; wq < 2; ++wq)
      #pragma unroll
      for (int nt = 2; nt < 4; ++nt)
        #pragma unroll
        for (int r = 0; r < 4; ++r)
          pb1[wq][(nt & 1)*4 + r] = (bf16)__builtin_amdgcn_exp2f(st[wq][nt][r]);

    __builtin_amdgcn_s_setprio(1);
    #pragma unroll
    for (int nt = 0; nt < 4; ++nt) {
      bf16x8 vf = *(const bf16x8*)&Vtc[(nt*16 + l15)*LP + 32 + quad*8];
      #pragma unroll
      for (int wq = 0; wq < 2; ++wq)
        o[wq][nt] = __builtin_amdgcn_mfma_f32_16x16x32_bf16(vf, pb1[wq], o[wq][nt], 0, 0, 0);
    }
    #pragma unroll
    for (int wq = 0; wq < 2; ++wq)
      osum[wq] = __builtin_amdgcn_mfma_f32_16x16x32_bf16(ones, pb1[wq], osum[wq], 0, 0, 0);
    __builtin_amdgcn_s_setprio(0);

    if (it < 31) {
      const int nxt = cur ^ 1;
      bf16* Ktn = Ktg + nxt*(64*LP);
      bf16* Vtn = Vtg + nxt*(64*LP);
      *(bf16x8*)&Ktn[r0s*LP + cs]     = ka0;
      *(bf16x8*)&Ktn[r0s*LP + cs + 8] = ka1;
      bf16x8 vv;
      vv[0]=va[0]; vv[1]=va[1]; vv[2]=va[2]; vv[3]=va[3];
      vv[4]=vb[0]; vv[5]=vb[1]; vv[6]=vb[2]; vv[7]=vb[3];
      *(bf16x8*)&Vtn[r0s*LP + cs] = vv;
      vv[0]=va[4]; vv[1]=va[5]; vv[2]=va[6]; vv[3]=va[7];
      vv[4]=vb[4]; vv[5]=vb[5]; vv[6]=vb[6]; vv[7]=vb[7];
      *(bf16x8*)&Vtn[r0s*LP + cs + 8] = vv;
      __syncthreads();
    }
  }

  // ---- combine the two k-groups, then normalize + write (group 0) ----
  __syncthreads();                       // all LDS tile reads done
  float* stash = (float*)smem;           // 4 waves x 64 lanes x 36 floats
  const int sidx = (wl*64 + lane) * 36;  // 144 B/lane, 16B-aligned
  if (g == 1) {
    #pragma unroll
    for (int wq = 0; wq < 2; ++wq)
      #pragma unroll
      for (int nt = 0; nt < 4; ++nt)
        *(f32x4*)&stash[sidx + (wq*4 + nt)*4] = o[wq][nt];
    stash[sidx + 32] = osum[0][0];
    stash[sidx + 33] = osum[1][0];
  }
  __syncthreads();
  if (g == 0) {
    #pragma unroll
    for (int wq = 0; wq < 2; ++wq)
      #pragma unroll
      for (int nt = 0; nt < 4; ++nt) {
        f32x4 p = *(const f32x4*)&stash[sidx + (wq*4 + nt)*4];
        #pragma unroll
        for (int r = 0; r < 4; ++r) o[wq][nt][r] += p[r];
      }
    const float s0 = osum[0][0] + stash[sidx + 32];
    const float s1 = osum[1][0] + stash[sidx + 33];

    const int b = bh >> 3, h = bh & 7;
    #pragma unroll
    for (int wq = 0; wq < 2; ++wq) {
      const float inv = 1.f / (wq == 0 ? s0 : s1);
      const size_t row = (size_t)(b*SS + q0 + wl*32 + wq*16 + l15) * CC + h*DD;
      #pragma unroll
      for (int nt = 0; nt < 4; ++nt) {
        bf16x4 ov;
        #pragma unroll
        for (int r = 0; r < 4; ++r) ov[r] = (bf16)(o[wq][nt][r] * inv);
        *(bf16x4*)&aout[row + nt*16 + quad*4] = ov;
      }
    }
  }
}

// ---------------------------------------------------------------------------
// Kernel 3: out = attn @ Wo^T + bo — R7: same global_load_lds linear-tile
// staging conversion as qkv_gemm (3 streams). Epilogue unchanged.
// ---------------------------------------------------------------------------
__global__ __launch_bounds__(256) void out_gemm(
    const bf16* __restrict__ A, const bf16* __restrict__ Wob,
    const float* __restrict__ bo, float* __restrict__ out)
{
  __shared__ bf16 Aa[64*64];
  __shared__ bf16 Ab[64*64];
  __shared__ bf16 Bt[64*64];
  const int m0 = blockIdx.x * 128;         // pair: m0 and m0+64
  const int n0 = blockIdx.y * 64;

  const int t = threadIdx.x;
  const int w = t >> 6;
  const int lane = t & 63;
  const int l15 = lane & 15;
  const int quad = lane >> 4;
  const int sr = lane >> 3;
  const int sc = (lane & 7) * 8;

  f32x4 aca[4], acb[4];
  #pragma unroll
  for (int i = 0; i < 4; ++i)
    #pragma unroll
    for (int j = 0; j < 4; ++j) { aca[i][j] = 0.f; acb[i][j] = 0.f; }

  for (int k0 = 0; k0 < CC; k0 += 64) {
    __syncthreads();
    {
      const bf16* pa = A + (size_t)(m0 + w*16 + sr) * CC + k0 + sc;
      gl16(pa,        &Aa[w*1024]);
      gl16(pa + 8*CC, &Aa[w*1024 + 512]);
      const bf16* pb = A + (size_t)(m0 + 64 + w*16 + sr) * CC + k0 + sc;
      gl16(pb,        &Ab[w*1024]);
      gl16(pb + 8*CC, &Ab[w*1024 + 512]);
      const bf16* p1 = Wob + (size_t)(n0 + w*16 + sr) * CC + k0 + sc;
      gl16(p1,        &Bt[w*1024]);
      gl16(p1 + 8*CC, &Bt[w*1024 + 512]);
    }
    __syncthreads();
    #pragma unroll
    for (int c = 0; c < 2; ++c) {
      bf16x8 afa = *(const bf16x8*)&Aa[(w*16 + l15)*64 + c*32 + quad*8];
      bf16x8 afb = *(const bf16x8*)&Ab[(w*16 + l15)*64 + c*32 + quad*8];
      #pragma unroll
      for (int nt = 0; nt < 4; ++nt) {
        bf16x8 bfr = *(const bf16x8*)&Bt[(nt*16 + l15)*64 + c*32 + quad*8];
        aca[nt] = __builtin_amdgcn_mfma_f32_16x16x32_bf16(afa, bfr, aca[nt], 0, 0, 0);
        acb[nt] = __builtin_amdgcn_mfma_f32_16x16x32_bf16(afb, bfr, acb[nt], 0, 0, 0);
      }
    }
  }

  #pragma unroll
  for (int nt = 0; nt < 4; ++nt) {
    const int ng = n0 + nt*16 + l15;
    const float bias = bo[ng];
    #pragma unroll
    for (int r = 0; r < 4; ++r) {
      const int mga = m0 + w*16 + quad*4 + r;
      out[(size_t)mga*CC + ng] = aca[nt][r] + bias;
      const int mgb = m0 + 64 + w*16 + quad*4 + r;
      out[(size_t)mgb*CC + ng] = acb[nt][r] + bias;
    }
  }
}

extern "C" void kernel_launch(void* const* d_in, const int* in_sizes, int n_in,
                              void* d_out, int out_size, void* d_ws, size_t ws_size,
                              hipStream_t stream) {
  const float* hs = (const float*)d_in[0];
  const float* Wq = (const float*)d_in[1];
  const float* Wk = (const float*)d_in[2];
  const float* Wv = (const float*)d_in[3];
  const float* Wo = (const float*)d_in[4];
  const float* bo = (const float*)d_in[5];
  float* out = (float*)d_out;

  const size_t PE = (size_t)BB*HH*SS*DD;      // 4,194,304 elems (8 MiB bf16)
  bf16* ws   = (bf16*)d_ws;
  bf16* qp   = ws;                 // [B][H][S][D] (scale folded via Wb)
  bf16* kp   = ws + PE;            // [B][H][S][D]
  bf16* vtp  = ws + 2*PE;          // [B][H][D][S]  (transposed)
  bf16* Xb   = ws + 3*PE;          // [MM][CC] bf16 (dead after qkv_gemm)
  bf16* aout = ws + 3*PE;          // [B][S][C]    (overwrites Xb after attn)
  bf16* Wb   = ws + 4*PE;          // [1536][512] bf16
  bf16* Wob  = Wb + 786432;        // [512][512] bf16 (own slot; ws>=40.5MB, uses 35.7MB)

  cvt_f32_bf16<<<dim3(2048),      256, 0, stream>>>(hs, Xb);        // X -> bf16
  cvt_w       <<<dim3(512),       256, 0, stream>>>(Wq, Wk, Wv, Wo, Wb, Wob);
  qkv_gemm<<<dim3(MM/128, 12),    256, 0, stream>>>(Xb, Wb, qp, kp, vtp);
  attn_fa <<<dim3(512),           512, 0, stream>>>(qp, kp, vtp, aout);
  out_gemm<<<dim3(MM/128, CC/64), 256, 0, stream>>>(aout, Wob, bo, out);
}